// Round 1
// baseline (770.737 us; speedup 1.0000x reference)
//
#include <hip/hip_runtime.h>
#include <float.h>

#define K_EMB 1024
#define D_EMB 256

// argmin GEMM tiling
#define MT 64      // rows (z vectors) per block
#define KC 64      // codes per k-chunk
#define DCK 32     // depth per chunk
#define LSTR 68    // padded LDS stride (floats); 68*4=272B keeps b128 alignment, spreads banks

// ---------------- row squared-norms (used for both z [N rows] and e [K rows]) --------------
__global__ void row_norms_kernel(const float* __restrict__ x, float* __restrict__ out, int nrows) {
  int row = blockIdx.x * 4 + (threadIdx.x >> 6);
  int lane = threadIdx.x & 63;
  if (row >= nrows) return;
  float4 v = ((const float4*)(x + (size_t)row * D_EMB))[lane];
  float s = v.x * v.x + v.y * v.y + v.z * v.z + v.w * v.w;
#pragma unroll
  for (int off = 32; off > 0; off >>= 1) s += __shfl_down(s, off, 64);
  if (lane == 0) out[row] = s;
}

// ---------------- distance argmin: d(n,k) = (t1[n] + t2[k]) - 2 * z_n . e_k ----------------
// block: 256 threads as 16x16 (tx: codes, ty: rows); each thread 4 rows x 4 codes.
__launch_bounds__(256, 4)
__global__ void argmin_kernel(const float* __restrict__ z, const float* __restrict__ emb,
                              const float* __restrict__ t1, const float* __restrict__ t2,
                              int* __restrict__ closest, float* __restrict__ idx_out) {
  __shared__ float zT[DCK * LSTR];  // zT[dd][r]  (transposed chunk)
  __shared__ float eT[DCK * LSTR];  // eT[dd][kk] (transposed chunk)
  const int tid = threadIdx.x;
  const int tx = tid & 15, ty = tid >> 4;
  const int row0 = blockIdx.x * MT;

  float myt1[4];
#pragma unroll
  for (int i = 0; i < 4; ++i) myt1[i] = t1[row0 + ty * 4 + i];

  float best[4] = {FLT_MAX, FLT_MAX, FLT_MAX, FLT_MAX};
  int bestk[4] = {0, 0, 0, 0};

  for (int kc = 0; kc < K_EMB / KC; ++kc) {
    float acc[4][4] = {};
    for (int dc = 0; dc < D_EMB / DCK; ++dc) {
      __syncthreads();
      // stage: 64 rows x 32 depth for both z-tile and e-tile, transposed into LDS
#pragma unroll
      for (int t = 0; t < 2; ++t) {
        int s = tid + 256 * t;  // 0..511
        int rr = s >> 3;        // 0..63
        int d4 = s & 7;         // 0..7 (float4 index along depth)
        float4 v = *(const float4*)(z + (size_t)(row0 + rr) * D_EMB + dc * DCK + d4 * 4);
        zT[(d4 * 4 + 0) * LSTR + rr] = v.x;
        zT[(d4 * 4 + 1) * LSTR + rr] = v.y;
        zT[(d4 * 4 + 2) * LSTR + rr] = v.z;
        zT[(d4 * 4 + 3) * LSTR + rr] = v.w;
        float4 w = *(const float4*)(emb + (size_t)(kc * KC + rr) * D_EMB + dc * DCK + d4 * 4);
        eT[(d4 * 4 + 0) * LSTR + rr] = w.x;
        eT[(d4 * 4 + 1) * LSTR + rr] = w.y;
        eT[(d4 * 4 + 2) * LSTR + rr] = w.z;
        eT[(d4 * 4 + 3) * LSTR + rr] = w.w;
      }
      __syncthreads();
#pragma unroll
      for (int dd = 0; dd < DCK; ++dd) {
        float4 a = *(const float4*)&zT[dd * LSTR + ty * 4];
        float4 b = *(const float4*)&eT[dd * LSTR + tx * 4];
        float aa[4] = {a.x, a.y, a.z, a.w};
        float bb[4] = {b.x, b.y, b.z, b.w};
#pragma unroll
        for (int i = 0; i < 4; ++i)
#pragma unroll
          for (int j = 0; j < 4; ++j) acc[i][j] += aa[i] * bb[j];
      }
    }
    // fold this k-chunk into the running argmin (ascending k => strict < keeps earliest)
#pragma unroll
    for (int j = 0; j < 4; ++j) {
      int k = kc * KC + tx * 4 + j;
      float t2k = t2[k];
#pragma unroll
      for (int i = 0; i < 4; ++i) {
        float dist = (myt1[i] + t2k) - 2.0f * acc[i][j];
        if (dist < best[i]) { best[i] = dist; bestk[i] = k; }
      }
    }
  }
  // reduce across the 16 tx lanes sharing each row (lanes of same ty within the wave)
#pragma unroll
  for (int m = 1; m <= 8; m <<= 1) {
#pragma unroll
    for (int i = 0; i < 4; ++i) {
      float od = __shfl_xor(best[i], m, 64);
      int ok = __shfl_xor(bestk[i], m, 64);
      if (od < best[i] || (od == best[i] && ok < bestk[i])) { best[i] = od; bestk[i] = ok; }
    }
  }
  if (tx == 0) {
#pragma unroll
    for (int i = 0; i < 4; ++i) {
      int r = row0 + ty * 4 + i;
      closest[r] = bestk[i];
      idx_out[r] = (float)bestk[i];
    }
  }
}

// ---------------- epilogue: gather, st_quantized, loss partials, counts, dw scatter -------
__global__ void epilogue_kernel(const float* __restrict__ z, const float* __restrict__ emb,
                                const int* __restrict__ closest, float* __restrict__ st_out,
                                float* __restrict__ loss_part, float* __restrict__ dw,
                                unsigned int* __restrict__ counts) {
  int row = blockIdx.x * 4 + (threadIdx.x >> 6);
  int lane = threadIdx.x & 63;
  int k = closest[row];
  float4 zv = ((const float4*)(z + (size_t)row * D_EMB))[lane];
  float4 ev = ((const float4*)(emb + (size_t)k * D_EMB))[lane];
  float dx = ev.x - zv.x, dy = ev.y - zv.y, dz = ev.z - zv.z, dwv = ev.w - zv.w;
  // st_quantized = z + (q - z), scalar stores (o_st is d_out+1: not 16B aligned)
  float* sp = st_out + (size_t)row * D_EMB + lane * 4;
  sp[0] = zv.x + dx; sp[1] = zv.y + dy; sp[2] = zv.z + dz; sp[3] = zv.w + dwv;
  float ls = dx * dx + dy * dy + dz * dz + dwv * dwv;
  float* dwp = dw + (size_t)k * D_EMB + lane * 4;
  atomicAdd(dwp + 0, zv.x);
  atomicAdd(dwp + 1, zv.y);
  atomicAdd(dwp + 2, zv.z);
  atomicAdd(dwp + 3, zv.w);
  if (lane == 0) atomicAdd(&counts[k], 1u);
#pragma unroll
  for (int off = 32; off > 0; off >>= 1) ls += __shfl_down(ls, off, 64);
  __shared__ float lsum[4];
  if (lane == 0) lsum[threadIdx.x >> 6] = ls;
  __syncthreads();
  if (threadIdx.x == 0) loss_part[blockIdx.x] = (lsum[0] + lsum[1]) + (lsum[2] + lsum[3]);
}

// ---------------- finalize 1: new_cluster + loss --------------------------------------------
__global__ void finalize1_kernel(const float* __restrict__ cs, const unsigned int* __restrict__ counts,
                                 const float* __restrict__ loss_part, int nlp,
                                 float* __restrict__ newc_ws, float* __restrict__ o_loss,
                                 float* __restrict__ o_ncl, int nrows) {
  int i = threadIdx.x;  // 0..1023
  __shared__ float red[1024];
  float pre = cs[i] * (float)0.99 + (float)counts[i] * (float)(1.0 - 0.99);
  red[i] = pre;
  __syncthreads();
  for (int s = 512; s > 0; s >>= 1) {
    if (i < s) red[i] += red[i + s];
    __syncthreads();
  }
  float n = red[0];
  float ncl = (pre + (float)1e-5) / (n + (float)(1024 * 1e-5)) * n;
  newc_ws[i] = ncl;
  o_ncl[i] = ncl;
  double lp = 0.0;
  for (int t = i; t < nlp; t += 1024) lp += (double)loss_part[t];
  __shared__ double dred[1024];
  dred[i] = lp;
  __syncthreads();
  for (int s = 512; s > 0; s >>= 1) {
    if (i < s) dred[i] += dred[i + s];
    __syncthreads();
  }
  if (i == 0) o_loss[0] = (float)(0.25 * (dred[0] / ((double)nrows * (double)D_EMB)));
}

// ---------------- finalize 2: new_ema and new_embeddings ------------------------------------
__global__ void finalize2_kernel(const float* __restrict__ ema, const float* __restrict__ dw,
                                 const float* __restrict__ newc, float* __restrict__ o_nema,
                                 float* __restrict__ o_nemb) {
  int idx = blockIdx.x * 256 + threadIdx.x;
  float ne = ema[idx] * (float)0.99 + dw[idx] * (float)(1.0 - 0.99);
  o_nema[idx] = ne;
  o_nemb[idx] = ne / newc[idx >> 8];
}

extern "C" void kernel_launch(void* const* d_in, const int* in_sizes, int n_in,
                              void* d_out, int out_size, void* d_ws, size_t ws_size,
                              hipStream_t stream) {
  const float* z = (const float*)d_in[0];
  const float* emb = (const float*)d_in[1];
  const float* ema = (const float*)d_in[2];
  const float* cs = (const float*)d_in[3];
  const int N = in_sizes[0] / D_EMB;  // 65536

  float* out = (float*)d_out;
  float* o_loss = out;                                  // [1]
  float* o_st = out + 1;                                // [N*256]
  float* o_idx = o_st + (size_t)N * D_EMB;              // [N]
  float* o_nemb = o_idx + N;                            // [K*256]
  float* o_ncl = o_nemb + (size_t)K_EMB * D_EMB;        // [K]
  float* o_nema = o_ncl + K_EMB;                        // [K*256]

  float* ws = (float*)d_ws;
  float* t1 = ws;                                      // N
  float* t2 = t1 + N;                                  // K
  int* closest = (int*)(t2 + K_EMB);                   // N
  float* loss_part = (float*)(closest + N);            // N/4
  unsigned int* counts = (unsigned int*)(loss_part + N / 4);  // K
  float* dw = (float*)(counts + K_EMB);                // K*256
  float* newc = dw + (size_t)K_EMB * D_EMB;            // K

  // counts + dw must start at zero every call (ws is not re-poisoned between replays)
  hipMemsetAsync(counts, 0, (size_t)(K_EMB + K_EMB * D_EMB) * sizeof(float), stream);

  row_norms_kernel<<<N / 4, 256, 0, stream>>>(z, t1, N);
  row_norms_kernel<<<K_EMB / 4, 256, 0, stream>>>(emb, t2, K_EMB);
  argmin_kernel<<<N / MT, 256, 0, stream>>>(z, emb, t1, t2, closest, o_idx);
  epilogue_kernel<<<N / 4, 256, 0, stream>>>(z, emb, closest, o_st, loss_part, dw, counts);
  finalize1_kernel<<<1, 1024, 0, stream>>>(cs, counts, loss_part, N / 4, newc, o_loss, o_ncl, N);
  finalize2_kernel<<<(K_EMB * D_EMB) / 256, 256, 0, stream>>>(ema, dw, newc, o_nema, o_nemb);
}

// Round 2
// 618.435 us; speedup vs baseline: 1.2463x; 1.2463x over previous
//
#include <hip/hip_runtime.h>
#include <float.h>
#include <stdint.h>

#define K_EMB 1024
#define D_EMB 256

typedef _Float16 half8 __attribute__((ext_vector_type(8)));
typedef _Float16 half4 __attribute__((ext_vector_type(4)));
typedef float f32x4_t __attribute__((ext_vector_type(4)));

// ============================ converts (+norms) ============================

__global__ void row_norms_kernel(const float* __restrict__ x, float* __restrict__ out, int nrows) {
  int row = blockIdx.x * 4 + (threadIdx.x >> 6);
  int lane = threadIdx.x & 63;
  if (row >= nrows) return;
  float4 v = ((const float4*)(x + (size_t)row * D_EMB))[lane];
  float s = v.x * v.x + v.y * v.y + v.z * v.z + v.w * v.w;
#pragma unroll
  for (int off = 32; off > 0; off >>= 1) s += __shfl_down(s, off, 64);
  if (lane == 0) out[row] = s;
}

__global__ void convert_z_kernel(const float* __restrict__ x, _Float16* __restrict__ xh,
                                 float* __restrict__ norms) {
  int row = blockIdx.x * 4 + (threadIdx.x >> 6);
  int lane = threadIdx.x & 63;
  float4 v = ((const float4*)(x + (size_t)row * D_EMB))[lane];
  float s = v.x * v.x + v.y * v.y + v.z * v.z + v.w * v.w;
#pragma unroll
  for (int off = 32; off > 0; off >>= 1) s += __shfl_down(s, off, 64);
  if (lane == 0) norms[row] = s;
  half4 h;
  h.x = (_Float16)v.x; h.y = (_Float16)v.y; h.z = (_Float16)v.z; h.w = (_Float16)v.w;
  ((half4*)xh)[(size_t)row * 64 + lane] = h;
}

__global__ void convert_e_kernel(const float* __restrict__ e, _Float16* __restrict__ ehp,
                                 _Float16* __restrict__ elp, float* __restrict__ t2) {
  int row = blockIdx.x * 4 + (threadIdx.x >> 6);
  int lane = threadIdx.x & 63;
  float4 v = ((const float4*)(e + (size_t)row * D_EMB))[lane];
  float s = v.x * v.x + v.y * v.y + v.z * v.z + v.w * v.w;
#pragma unroll
  for (int off = 32; off > 0; off >>= 1) s += __shfl_down(s, off, 64);
  if (lane == 0) t2[row] = s;
  half4 h, l;
  h.x = (_Float16)v.x; h.y = (_Float16)v.y; h.z = (_Float16)v.z; h.w = (_Float16)v.w;
  l.x = (_Float16)((v.x - (float)h.x) * 4096.f);
  l.y = (_Float16)((v.y - (float)h.y) * 4096.f);
  l.z = (_Float16)((v.z - (float)h.z) * 4096.f);
  l.w = (_Float16)((v.w - (float)h.w) * 4096.f);
  ((half4*)ehp)[(size_t)row * 64 + lane] = h;
  ((half4*)elp)[(size_t)row * 64 + lane] = l;
}

// ============================ MFMA argmin ============================
// dist_fine(n,k) = t2[k] - 2*(acc1 + acc2/4096); per-row min1/min2/k1 tracked.
// Rows with (min2-min1) < DELTA are flagged for exact-f32 fixup.

#define BM 256
#define CCH 64
#define NCH (K_EMB / CCH)
#define DELTA 1.5e-4f

__launch_bounds__(512, 2)
__global__ void argmin_mfma_kernel(const _Float16* __restrict__ zh,
                                   const _Float16* __restrict__ eh,
                                   const _Float16* __restrict__ els,
                                   const float* __restrict__ t2,
                                   int* __restrict__ closest,
                                   float* __restrict__ idx_out,
                                   unsigned int* __restrict__ flag_cnt,
                                   unsigned int* __restrict__ flaglist) {
  // two planes (eh, el), 64 codes x 256 depth, XOR-swizzled: elem ^= (code&7)<<3
  __shared__ _Float16 ebuf[2 * CCH * D_EMB];  // 64 KiB
  const int tid = threadIdx.x;
  const int wid = tid >> 6;
  const int lane = tid & 63;
  const int c = lane & 15, g = lane >> 4;
  const int row0 = blockIdx.x * BM + wid * 32;

  // resident A fragments: 2 row-frags x 8 depth-frags (z rows row0+fr*16+c)
  half8 A[2][8];
#pragma unroll
  for (int fr = 0; fr < 2; ++fr)
#pragma unroll
    for (int df = 0; df < 8; ++df)
      A[fr][df] = *(const half8*)(zh + (size_t)(row0 + fr * 16 + c) * D_EMB + df * 32 + g * 8);

  float m1[8], m2[8];
  int k1[8];
#pragma unroll
  for (int s = 0; s < 8; ++s) { m1[s] = FLT_MAX; m2[s] = FLT_MAX; k1[s] = 0; }

  // staging role for this thread: plane, code, quarter(128B)
  const int sp = tid >> 8;
  const int scode = (tid >> 2) & 63;
  const int sq = tid & 3;
  const _Float16* splane = sp ? els : eh;
  const int swz_w = (scode & 7) << 3;
  const int rswz = (c & 7) << 3;

  for (int cb = 0; cb < NCH; ++cb) {
    __syncthreads();
    {
      const _Float16* src = splane + (size_t)(cb * CCH + scode) * D_EMB + sq * 64;
      _Float16* dstbase = ebuf + sp * (CCH * D_EMB) + scode * D_EMB;
#pragma unroll
      for (int u = 0; u < 8; ++u) {
        int elem = sq * 64 + u * 8;
        *(half8*)(dstbase + (elem ^ swz_w)) = *(const half8*)(src + u * 8);
      }
    }
    __syncthreads();

    f32x4_t acc1[2][4], acc2[2][4];
#pragma unroll
    for (int fr = 0; fr < 2; ++fr)
#pragma unroll
      for (int fc = 0; fc < 4; ++fc) {
        acc1[fr][fc] = (f32x4_t){0.f, 0.f, 0.f, 0.f};
        acc2[fr][fc] = (f32x4_t){0.f, 0.f, 0.f, 0.f};
      }

#pragma unroll
    for (int d = 0; d < 8; ++d) {
      half8 Bh[4], Bl[4];
#pragma unroll
      for (int fc = 0; fc < 4; ++fc) {
        const int elem = (d * 32 + g * 8) ^ rswz;
        const int codeoff = (fc * 16 + c) * D_EMB;
        Bh[fc] = *(const half8*)(ebuf + codeoff + elem);
        Bl[fc] = *(const half8*)(ebuf + CCH * D_EMB + codeoff + elem);
      }
#pragma unroll
      for (int fr = 0; fr < 2; ++fr)
#pragma unroll
        for (int fc = 0; fc < 4; ++fc) {
          acc1[fr][fc] = __builtin_amdgcn_mfma_f32_16x16x32_f16(A[fr][d], Bh[fc], acc1[fr][fc], 0, 0, 0);
          acc2[fr][fc] = __builtin_amdgcn_mfma_f32_16x16x32_f16(A[fr][d], Bl[fc], acc2[fr][fc], 0, 0, 0);
        }
    }

#pragma unroll
    for (int fc = 0; fc < 4; ++fc) {
      const int kk = cb * CCH + fc * 16 + c;
      const float t2c = t2[kk];
#pragma unroll
      for (int fr = 0; fr < 2; ++fr)
#pragma unroll
        for (int r = 0; r < 4; ++r) {
          float dv = fmaf(-2.f, acc1[fr][fc][r], t2c);
          dv = fmaf(-2.f / 4096.f, acc2[fr][fc][r], dv);
          const int s = fr * 4 + r;
          const bool lt = dv < m1[s];
          m2[s] = lt ? m1[s] : fminf(m2[s], dv);
          m1[s] = lt ? dv : m1[s];
          k1[s] = lt ? kk : k1[s];
        }
    }
  }

  // reduce (m1,k1,m2) across the 16 lanes sharing g (xor low-4 bits)
#pragma unroll
  for (int m = 1; m <= 8; m <<= 1) {
#pragma unroll
    for (int s = 0; s < 8; ++s) {
      const float om1 = __shfl_xor(m1[s], m, 64);
      const float om2 = __shfl_xor(m2[s], m, 64);
      const int ok1 = __shfl_xor(k1[s], m, 64);
      const float hi = fmaxf(m1[s], om1);
      m2[s] = fminf(fminf(m2[s], om2), hi);
      if (om1 < m1[s]) { m1[s] = om1; k1[s] = ok1; }
    }
  }

  if (c == 0) {
#pragma unroll
    for (int s = 0; s < 8; ++s) {
      const int fr = s >> 2, r = s & 3;
      const int row = row0 + fr * 16 + g * 4 + r;
      closest[row] = k1[s];
      idx_out[row] = (float)k1[s];
      if (m2[s] - m1[s] < DELTA) {
        unsigned int p = atomicAdd(flag_cnt, 1u);
        flaglist[p] = (unsigned int)row;
      }
    }
  }
}

// ============================ exact fixup for flagged rows ============================
// Replicates the reference f32 rounding: d = (t1+t2[k]) - 2*dot, lowest-index tie-break.

__global__ void fixup_kernel(const float* __restrict__ z, const float* __restrict__ emb,
                             const float* __restrict__ t1, const float* __restrict__ t2,
                             const unsigned int* __restrict__ flag_cnt,
                             const unsigned int* __restrict__ flaglist,
                             int* __restrict__ closest, float* __restrict__ idx_out) {
  __shared__ float zs[4][D_EMB];
  const int tid = threadIdx.x;
  const int w = tid >> 6, lane = tid & 63;
  const unsigned int cnt = *flag_cnt;
  const unsigned int njobs = (cnt + 3) >> 2;
  for (unsigned int job = blockIdx.x; job < njobs; job += gridDim.x) {
    __syncthreads();
    const unsigned int fi = job * 4 + w;
    int row = -1;
    if (fi < cnt) {
      row = (int)flaglist[fi];
      ((float4*)zs[w])[lane] = ((const float4*)(z + (size_t)row * D_EMB))[lane];
    }
    __syncthreads();
    if (fi >= cnt) continue;
    const float tt1 = t1[row];
    float best = FLT_MAX;
    int bk = 0;
    const float4* zp = (const float4*)zs[w];
    for (int cc = 0; cc < 16; ++cc) {
      const int k = lane + cc * 64;
      const float4* ep = (const float4*)(emb + (size_t)k * D_EMB);
      float s0 = 0.f, s1 = 0.f, s2 = 0.f, s3 = 0.f;
#pragma unroll 8
      for (int i = 0; i < 64; ++i) {
        const float4 ev = ep[i];
        const float4 zv = zp[i];
        s0 = fmaf(zv.x, ev.x, s0); s1 = fmaf(zv.y, ev.y, s1);
        s2 = fmaf(zv.z, ev.z, s2); s3 = fmaf(zv.w, ev.w, s3);
      }
      const float dot = (s0 + s1) + (s2 + s3);
      const float dv = (tt1 + t2[k]) - 2.f * dot;
      if (dv < best || (dv == best && k < bk)) { best = dv; bk = k; }
    }
#pragma unroll
    for (int m = 1; m <= 32; m <<= 1) {
      const float ob = __shfl_xor(best, m, 64);
      const int okk = __shfl_xor(bk, m, 64);
      if (ob < best || (ob == best && okk < bk)) { best = ob; bk = okk; }
    }
    if (lane == 0) { closest[row] = bk; idx_out[row] = (float)bk; }
  }
}

// ============================ legacy f32 argmin (ws fallback) ============================

#define MT 64
#define KC 64
#define DCK 32
#define LSTR 68

__launch_bounds__(256, 4)
__global__ void argmin_kernel(const float* __restrict__ z, const float* __restrict__ emb,
                              const float* __restrict__ t1, const float* __restrict__ t2,
                              int* __restrict__ closest, float* __restrict__ idx_out) {
  __shared__ float zT[DCK * LSTR];
  __shared__ float eT[DCK * LSTR];
  const int tid = threadIdx.x;
  const int tx = tid & 15, ty = tid >> 4;
  const int row0 = blockIdx.x * MT;

  float myt1[4];
#pragma unroll
  for (int i = 0; i < 4; ++i) myt1[i] = t1[row0 + ty * 4 + i];

  float best[4] = {FLT_MAX, FLT_MAX, FLT_MAX, FLT_MAX};
  int bestk[4] = {0, 0, 0, 0};

  for (int kc = 0; kc < K_EMB / KC; ++kc) {
    float acc[4][4] = {};
    for (int dc = 0; dc < D_EMB / DCK; ++dc) {
      __syncthreads();
#pragma unroll
      for (int t = 0; t < 2; ++t) {
        int s = tid + 256 * t;
        int rr = s >> 3;
        int d4 = s & 7;
        float4 v = *(const float4*)(z + (size_t)(row0 + rr) * D_EMB + dc * DCK + d4 * 4);
        zT[(d4 * 4 + 0) * LSTR + rr] = v.x;
        zT[(d4 * 4 + 1) * LSTR + rr] = v.y;
        zT[(d4 * 4 + 2) * LSTR + rr] = v.z;
        zT[(d4 * 4 + 3) * LSTR + rr] = v.w;
        float4 w2 = *(const float4*)(emb + (size_t)(kc * KC + rr) * D_EMB + dc * DCK + d4 * 4);
        eT[(d4 * 4 + 0) * LSTR + rr] = w2.x;
        eT[(d4 * 4 + 1) * LSTR + rr] = w2.y;
        eT[(d4 * 4 + 2) * LSTR + rr] = w2.z;
        eT[(d4 * 4 + 3) * LSTR + rr] = w2.w;
      }
      __syncthreads();
#pragma unroll
      for (int dd = 0; dd < DCK; ++dd) {
        float4 a = *(const float4*)&zT[dd * LSTR + ty * 4];
        float4 b = *(const float4*)&eT[dd * LSTR + tx * 4];
        float aa[4] = {a.x, a.y, a.z, a.w};
        float bb[4] = {b.x, b.y, b.z, b.w};
#pragma unroll
        for (int i = 0; i < 4; ++i)
#pragma unroll
          for (int j = 0; j < 4; ++j) acc[i][j] += aa[i] * bb[j];
      }
    }
#pragma unroll
    for (int j = 0; j < 4; ++j) {
      int k = kc * KC + tx * 4 + j;
      float t2k = t2[k];
#pragma unroll
      for (int i = 0; i < 4; ++i) {
        float dist = (myt1[i] + t2k) - 2.0f * acc[i][j];
        if (dist < best[i]) { best[i] = dist; bestk[i] = k; }
      }
    }
  }
#pragma unroll
  for (int m = 1; m <= 8; m <<= 1) {
#pragma unroll
    for (int i = 0; i < 4; ++i) {
      float od = __shfl_xor(best[i], m, 64);
      int ok = __shfl_xor(bestk[i], m, 64);
      if (od < best[i] || (od == best[i] && ok < bestk[i])) { best[i] = od; bestk[i] = ok; }
    }
  }
  if (tx == 0) {
#pragma unroll
    for (int i = 0; i < 4; ++i) {
      int r = row0 + ty * 4 + i;
      closest[r] = bestk[i];
      idx_out[r] = (float)bestk[i];
    }
  }
}

// ============================ epilogue + finalize ============================

__global__ void epilogue_kernel(const float* __restrict__ z, const float* __restrict__ emb,
                                const int* __restrict__ closest, float* __restrict__ st_out,
                                float* __restrict__ loss_part, float* __restrict__ dw,
                                unsigned int* __restrict__ counts) {
  int row = blockIdx.x * 4 + (threadIdx.x >> 6);
  int lane = threadIdx.x & 63;
  int k = closest[row];
  float4 zv = ((const float4*)(z + (size_t)row * D_EMB))[lane];
  float4 ev = ((const float4*)(emb + (size_t)k * D_EMB))[lane];
  float dx = ev.x - zv.x, dy = ev.y - zv.y, dz = ev.z - zv.z, dwv = ev.w - zv.w;
  float* sp = st_out + (size_t)row * D_EMB + lane * 4;
  sp[0] = zv.x + dx; sp[1] = zv.y + dy; sp[2] = zv.z + dz; sp[3] = zv.w + dwv;
  float ls = dx * dx + dy * dy + dz * dz + dwv * dwv;
  float* dwp = dw + (size_t)k * D_EMB + lane * 4;
  atomicAdd(dwp + 0, zv.x);
  atomicAdd(dwp + 1, zv.y);
  atomicAdd(dwp + 2, zv.z);
  atomicAdd(dwp + 3, zv.w);
  if (lane == 0) atomicAdd(&counts[k], 1u);
#pragma unroll
  for (int off = 32; off > 0; off >>= 1) ls += __shfl_down(ls, off, 64);
  __shared__ float lsum[4];
  if (lane == 0) lsum[threadIdx.x >> 6] = ls;
  __syncthreads();
  if (threadIdx.x == 0) loss_part[blockIdx.x] = (lsum[0] + lsum[1]) + (lsum[2] + lsum[3]);
}

__global__ void finalize1_kernel(const float* __restrict__ cs, const unsigned int* __restrict__ counts,
                                 const float* __restrict__ loss_part, int nlp,
                                 float* __restrict__ newc_ws, float* __restrict__ o_loss,
                                 float* __restrict__ o_ncl, int nrows) {
  int i = threadIdx.x;
  __shared__ float red[1024];
  float pre = cs[i] * 0.99f + (float)counts[i] * (float)(1.0 - 0.99);
  red[i] = pre;
  __syncthreads();
  for (int s = 512; s > 0; s >>= 1) {
    if (i < s) red[i] += red[i + s];
    __syncthreads();
  }
  float n = red[0];
  float ncl = (pre + 1e-5f) / (n + (float)(1024 * 1e-5)) * n;
  newc_ws[i] = ncl;
  o_ncl[i] = ncl;
  double lp = 0.0;
  for (int t = i; t < nlp; t += 1024) lp += (double)loss_part[t];
  __shared__ double dred[1024];
  dred[i] = lp;
  __syncthreads();
  for (int s = 512; s > 0; s >>= 1) {
    if (i < s) dred[i] += dred[i + s];
    __syncthreads();
  }
  if (i == 0) o_loss[0] = (float)(0.25 * (dred[0] / ((double)nrows * (double)D_EMB)));
}

__global__ void finalize2_kernel(const float* __restrict__ ema, const float* __restrict__ dw,
                                 const float* __restrict__ newc, float* __restrict__ o_nema,
                                 float* __restrict__ o_nemb) {
  int idx = blockIdx.x * 256 + threadIdx.x;
  float ne = ema[idx] * 0.99f + dw[idx] * (float)(1.0 - 0.99);
  o_nema[idx] = ne;
  o_nemb[idx] = ne / newc[idx >> 8];
}

// ============================ launcher ============================

extern "C" void kernel_launch(void* const* d_in, const int* in_sizes, int n_in,
                              void* d_out, int out_size, void* d_ws, size_t ws_size,
                              hipStream_t stream) {
  const float* z = (const float*)d_in[0];
  const float* emb = (const float*)d_in[1];
  const float* ema = (const float*)d_in[2];
  const float* cs = (const float*)d_in[3];
  const int N = in_sizes[0] / D_EMB;  // 65536

  float* out = (float*)d_out;
  float* o_loss = out;
  float* o_st = out + 1;
  float* o_idx = o_st + (size_t)N * D_EMB;
  float* o_nemb = o_idx + N;
  float* o_ncl = o_nemb + (size_t)K_EMB * D_EMB;
  float* o_nema = o_ncl + K_EMB;

  float* ws = (float*)d_ws;

  // ---- fast-path ws layout ----
  float* t1 = ws;                                             // N
  float* t2 = t1 + N;                                         // K
  int* closest = (int*)(t2 + K_EMB);                          // N
  float* loss_part = (float*)(closest + N);                   // N/4
  float* newc = loss_part + N / 4;                            // K
  _Float16* ehp = (_Float16*)(newc + K_EMB);                  // K*D halves
  _Float16* elp = ehp + (size_t)K_EMB * D_EMB;                // K*D halves
  unsigned int* flaglist = (unsigned int*)(elp + (size_t)K_EMB * D_EMB);  // N
  unsigned int* counts = flaglist + N;                        // K   (zeroed)
  float* dwb = (float*)(counts + K_EMB);                      // K*D (zeroed)
  unsigned int* flag_cnt = (unsigned int*)(dwb + (size_t)K_EMB * D_EMB);  // 1 (zeroed)
  size_t need_fast = (size_t)((char*)(flag_cnt + 1) - (char*)ws);

  if (ws_size >= need_fast) {
    // zh (N*D f16 = 32 MB) lives in the o_st output region (overwritten by epilogue later)
    uintptr_t zp_ = ((uintptr_t)o_st + 15) & ~(uintptr_t)15;
    _Float16* zh = (_Float16*)zp_;

    hipMemsetAsync(counts, 0, (size_t)(K_EMB + (size_t)K_EMB * D_EMB + 1) * 4, stream);
    convert_z_kernel<<<N / 4, 256, 0, stream>>>(z, zh, t1);
    convert_e_kernel<<<K_EMB / 4, 256, 0, stream>>>(emb, ehp, elp, t2);
    argmin_mfma_kernel<<<N / BM, 512, 0, stream>>>(zh, ehp, elp, t2, closest, o_idx,
                                                   flag_cnt, flaglist);
    fixup_kernel<<<1024, 256, 0, stream>>>(z, emb, t1, t2, flag_cnt, flaglist, closest, o_idx);
    epilogue_kernel<<<N / 4, 256, 0, stream>>>(z, emb, closest, o_st, loss_part, dwb, counts);
    finalize1_kernel<<<1, 1024, 0, stream>>>(cs, counts, loss_part, N / 4, newc, o_loss, o_ncl, N);
    finalize2_kernel<<<(K_EMB * D_EMB) / 256, 256, 0, stream>>>(ema, dwb, newc, o_nema, o_nemb);
  } else {
    // ---- legacy compact layout (round-1 path) ----
    float* lt1 = ws;
    float* lt2 = lt1 + N;
    int* lclosest = (int*)(lt2 + K_EMB);
    float* lloss = (float*)(lclosest + N);
    unsigned int* lcounts = (unsigned int*)(lloss + N / 4);
    float* ldw = (float*)(lcounts + K_EMB);
    float* lnewc = ldw + (size_t)K_EMB * D_EMB;

    hipMemsetAsync(lcounts, 0, (size_t)(K_EMB + (size_t)K_EMB * D_EMB) * 4, stream);
    row_norms_kernel<<<N / 4, 256, 0, stream>>>(z, lt1, N);
    row_norms_kernel<<<K_EMB / 4, 256, 0, stream>>>(emb, lt2, K_EMB);
    argmin_kernel<<<N / MT, 256, 0, stream>>>(z, emb, lt1, lt2, lclosest, o_idx);
    epilogue_kernel<<<N / 4, 256, 0, stream>>>(z, emb, lclosest, o_st, lloss, ldw, lcounts);
    finalize1_kernel<<<1, 1024, 0, stream>>>(cs, lcounts, lloss, N / 4, lnewc, o_loss, o_ncl, N);
    finalize2_kernel<<<(K_EMB * D_EMB) / 256, 256, 0, stream>>>(ema, ldw, lnewc, o_nema, o_nemb);
  }
}

// Round 3
// 242.400 us; speedup vs baseline: 3.1796x; 2.5513x over previous
//
#include <hip/hip_runtime.h>
#include <float.h>
#include <stdint.h>

#define K_EMB 1024
#define D_EMB 256

typedef _Float16 half8 __attribute__((ext_vector_type(8)));
typedef _Float16 half4 __attribute__((ext_vector_type(4)));
typedef float f32x4_t __attribute__((ext_vector_type(4)));

// ============================ converts (+norms) ============================

__global__ void convert_z_kernel(const float* __restrict__ x, _Float16* __restrict__ xh,
                                 float* __restrict__ norms) {
  int row = blockIdx.x * 4 + (threadIdx.x >> 6);
  int lane = threadIdx.x & 63;
  float4 v = ((const float4*)(x + (size_t)row * D_EMB))[lane];
  float s = v.x * v.x + v.y * v.y + v.z * v.z + v.w * v.w;
#pragma unroll
  for (int off = 32; off > 0; off >>= 1) s += __shfl_down(s, off, 64);
  if (lane == 0) norms[row] = s;
  half4 h;
  h.x = (_Float16)v.x; h.y = (_Float16)v.y; h.z = (_Float16)v.z; h.w = (_Float16)v.w;
  ((half4*)xh)[(size_t)row * 64 + lane] = h;
}

__global__ void convert_e_kernel(const float* __restrict__ e, _Float16* __restrict__ ehp,
                                 float* __restrict__ t2) {
  int row = blockIdx.x * 4 + (threadIdx.x >> 6);
  int lane = threadIdx.x & 63;
  float4 v = ((const float4*)(e + (size_t)row * D_EMB))[lane];
  float s = v.x * v.x + v.y * v.y + v.z * v.z + v.w * v.w;
#pragma unroll
  for (int off = 32; off > 0; off >>= 1) s += __shfl_down(s, off, 64);
  if (lane == 0) t2[row] = s;
  half4 h;
  h.x = (_Float16)v.x; h.y = (_Float16)v.y; h.z = (_Float16)v.z; h.w = (_Float16)v.w;
  ((half4*)ehp)[(size_t)row * 64 + lane] = h;
}

// ============================ MFMA argmin (single f16 plane) ============================
// fine dist(n,k) = t2[k] - 2*(zh_n . eh_k); rows with (min2-min1) < DELTA get exact fixup.

#define BM 256
#define CCH 64
#define NCH (K_EMB / CCH)
#define DELTA 1.5e-4f

__launch_bounds__(512, 2)
__global__ void argmin_mfma_kernel(const _Float16* __restrict__ zh,
                                   const _Float16* __restrict__ eh,
                                   const float* __restrict__ t2,
                                   int* __restrict__ closest,
                                   float* __restrict__ idx_out,
                                   unsigned int* __restrict__ flag_cnt,
                                   unsigned int* __restrict__ flaglist) {
  __shared__ _Float16 ebuf[CCH * D_EMB];  // 32 KiB, XOR-swizzled: elem ^= (code&7)<<3
  const int tid = threadIdx.x;
  const int wid = tid >> 6;
  const int lane = tid & 63;
  const int c = lane & 15, g = lane >> 4;
  const int row0 = blockIdx.x * BM + wid * 32;

  // resident A fragments: 2 row-frags x 8 depth-frags
  half8 A[2][8];
#pragma unroll
  for (int fr = 0; fr < 2; ++fr)
#pragma unroll
    for (int df = 0; df < 8; ++df)
      A[fr][df] = *(const half8*)(zh + (size_t)(row0 + fr * 16 + c) * D_EMB + df * 32 + g * 8);

  float m1[8], m2[8];
  int k1[8];
#pragma unroll
  for (int s = 0; s < 8; ++s) { m1[s] = FLT_MAX; m2[s] = FLT_MAX; k1[s] = 0; }

  const int scode = tid >> 3;            // 0..63
  const int s8 = tid & 7;                // 0..7
  const int swz_w = (scode & 7) << 3;
  const int rswz = (c & 7) << 3;

  for (int cb = 0; cb < NCH; ++cb) {
    __syncthreads();
    {
      const _Float16* src = eh + (size_t)(cb * CCH + scode) * D_EMB + s8 * 32;
      _Float16* dst = ebuf + scode * D_EMB;
#pragma unroll
      for (int u = 0; u < 4; ++u) {
        int elem = s8 * 32 + u * 8;
        *(half8*)(dst + (elem ^ swz_w)) = *(const half8*)(src + u * 8);
      }
    }
    __syncthreads();

    f32x4_t acc[2][4];
#pragma unroll
    for (int fr = 0; fr < 2; ++fr)
#pragma unroll
      for (int fc = 0; fc < 4; ++fc) acc[fr][fc] = (f32x4_t){0.f, 0.f, 0.f, 0.f};

#pragma unroll
    for (int d = 0; d < 8; ++d) {
      half8 Bh[4];
#pragma unroll
      for (int fc = 0; fc < 4; ++fc) {
        const int elem = (d * 32 + g * 8) ^ rswz;
        Bh[fc] = *(const half8*)(ebuf + (fc * 16 + c) * D_EMB + elem);
      }
#pragma unroll
      for (int fr = 0; fr < 2; ++fr)
#pragma unroll
        for (int fc = 0; fc < 4; ++fc)
          acc[fr][fc] = __builtin_amdgcn_mfma_f32_16x16x32_f16(A[fr][d], Bh[fc], acc[fr][fc], 0, 0, 0);
    }

#pragma unroll
    for (int fc = 0; fc < 4; ++fc) {
      const int kk = cb * CCH + fc * 16 + c;
      const float t2c = t2[kk];
#pragma unroll
      for (int fr = 0; fr < 2; ++fr)
#pragma unroll
        for (int r = 0; r < 4; ++r) {
          const float dv = fmaf(-2.f, acc[fr][fc][r], t2c);
          const int s = fr * 4 + r;
          const bool lt = dv < m1[s];
          m2[s] = lt ? m1[s] : fminf(m2[s], dv);
          m1[s] = lt ? dv : m1[s];
          k1[s] = lt ? kk : k1[s];
        }
    }
  }

#pragma unroll
  for (int m = 1; m <= 8; m <<= 1) {
#pragma unroll
    for (int s = 0; s < 8; ++s) {
      const float om1 = __shfl_xor(m1[s], m, 64);
      const float om2 = __shfl_xor(m2[s], m, 64);
      const int ok1 = __shfl_xor(k1[s], m, 64);
      const float hi = fmaxf(m1[s], om1);
      m2[s] = fminf(fminf(m2[s], om2), hi);
      if (om1 < m1[s]) { m1[s] = om1; k1[s] = ok1; }
    }
  }

  if (c == 0) {
#pragma unroll
    for (int s = 0; s < 8; ++s) {
      const int fr = s >> 2, r = s & 3;
      const int row = row0 + fr * 16 + g * 4 + r;
      closest[row] = k1[s];
      idx_out[row] = (float)k1[s];
      if (m2[s] - m1[s] < DELTA) {
        unsigned int p = atomicAdd(flag_cnt, 1u);
        flaglist[p] = (unsigned int)row;
      }
    }
  }
}

// ============================ exact fixup (register-blocked, 8 rows/block) ============================

#define FB_ROWS 8

__launch_bounds__(256, 2)
__global__ void fixup_kernel(const float* __restrict__ z, const float* __restrict__ emb,
                             const float* __restrict__ t1, const float* __restrict__ t2,
                             const unsigned int* __restrict__ flag_cnt,
                             const unsigned int* __restrict__ flaglist,
                             int* __restrict__ closest, float* __restrict__ idx_out) {
  __shared__ float4 zs[FB_ROWS][64];
  __shared__ float t1s[FB_ROWS];
  __shared__ int rows_s[FB_ROWS];
  __shared__ float redm[4][FB_ROWS];
  __shared__ int redk[4][FB_ROWS];
  const int tid = threadIdx.x;
  const int lane = tid & 63, wv = tid >> 6;
  const unsigned int cnt = *flag_cnt;
  const unsigned int njobs = (cnt + FB_ROWS - 1) / FB_ROWS;
  for (unsigned int job = blockIdx.x; job < njobs; job += gridDim.x) {
    __syncthreads();
    if (tid < FB_ROWS) {
      const unsigned int fi = job * FB_ROWS + tid;
      const int row = (fi < cnt) ? (int)flaglist[fi] : -1;
      rows_s[tid] = row;
      t1s[tid] = (row >= 0) ? t1[row] : 0.f;
    }
    __syncthreads();
#pragma unroll
    for (int u = 0; u < 2; ++u) {
      const int lin = tid + 256 * u;
      const int r = lin >> 6, i = lin & 63;
      const int row = rows_s[r];
      zs[r][i] = (row >= 0) ? ((const float4*)(z + (size_t)row * D_EMB))[i]
                            : (float4){0.f, 0.f, 0.f, 0.f};
    }
    __syncthreads();
    // thread owns codes 4*tid .. 4*tid+3
    float acc[FB_ROWS][4] = {};
    const float4* e0 = (const float4*)(emb + (size_t)(4 * tid + 0) * D_EMB);
    const float4* e1 = (const float4*)(emb + (size_t)(4 * tid + 1) * D_EMB);
    const float4* e2 = (const float4*)(emb + (size_t)(4 * tid + 2) * D_EMB);
    const float4* e3 = (const float4*)(emb + (size_t)(4 * tid + 3) * D_EMB);
    for (int i = 0; i < 64; ++i) {
      const float4 v0 = e0[i], v1 = e1[i], v2 = e2[i], v3 = e3[i];
#pragma unroll
      for (int r = 0; r < FB_ROWS; ++r) {
        const float4 zv = zs[r][i];
        acc[r][0] = fmaf(zv.x, v0.x, acc[r][0]); acc[r][0] = fmaf(zv.y, v0.y, acc[r][0]);
        acc[r][0] = fmaf(zv.z, v0.z, acc[r][0]); acc[r][0] = fmaf(zv.w, v0.w, acc[r][0]);
        acc[r][1] = fmaf(zv.x, v1.x, acc[r][1]); acc[r][1] = fmaf(zv.y, v1.y, acc[r][1]);
        acc[r][1] = fmaf(zv.z, v1.z, acc[r][1]); acc[r][1] = fmaf(zv.w, v1.w, acc[r][1]);
        acc[r][2] = fmaf(zv.x, v2.x, acc[r][2]); acc[r][2] = fmaf(zv.y, v2.y, acc[r][2]);
        acc[r][2] = fmaf(zv.z, v2.z, acc[r][2]); acc[r][2] = fmaf(zv.w, v2.w, acc[r][2]);
        acc[r][3] = fmaf(zv.x, v3.x, acc[r][3]); acc[r][3] = fmaf(zv.y, v3.y, acc[r][3]);
        acc[r][3] = fmaf(zv.z, v3.z, acc[r][3]); acc[r][3] = fmaf(zv.w, v3.w, acc[r][3]);
      }
    }
    float best[FB_ROWS];
    int bk[FB_ROWS];
#pragma unroll
    for (int r = 0; r < FB_ROWS; ++r) { best[r] = FLT_MAX; bk[r] = 0; }
#pragma unroll
    for (int cc = 0; cc < 4; ++cc) {
      const int k = 4 * tid + cc;
      const float t2k = t2[k];
#pragma unroll
      for (int r = 0; r < FB_ROWS; ++r) {
        const float dv = (t1s[r] + t2k) - 2.f * acc[r][cc];
        if (dv < best[r] || (dv == best[r] && k < bk[r])) { best[r] = dv; bk[r] = k; }
      }
    }
#pragma unroll
    for (int m = 1; m <= 32; m <<= 1) {
#pragma unroll
      for (int r = 0; r < FB_ROWS; ++r) {
        const float ob = __shfl_xor(best[r], m, 64);
        const int ok = __shfl_xor(bk[r], m, 64);
        if (ob < best[r] || (ob == best[r] && ok < bk[r])) { best[r] = ob; bk[r] = ok; }
      }
    }
    if (lane == 0) {
#pragma unroll
      for (int r = 0; r < FB_ROWS; ++r) { redm[wv][r] = best[r]; redk[wv][r] = bk[r]; }
    }
    __syncthreads();
    if (tid < FB_ROWS) {
      const int r = tid;
      float b = redm[0][r];
      int k = redk[0][r];
#pragma unroll
      for (int w = 1; w < 4; ++w)
        if (redm[w][r] < b || (redm[w][r] == b && redk[w][r] < k)) { b = redm[w][r]; k = redk[w][r]; }
      const int row = rows_s[r];
      if (row >= 0) { closest[row] = k; idx_out[row] = (float)k; }
    }
  }
}

// ============================ counting sort of rows by code ============================

__global__ void hist1_kernel(const int* __restrict__ closest, unsigned int* __restrict__ rank,
                             unsigned int* __restrict__ blockhist) {
  __shared__ unsigned int lh[K_EMB];
  const int t = threadIdx.x;  // 1024
  lh[t] = 0;
  __syncthreads();
  const int row = blockIdx.x * 1024 + t;
  rank[row] = atomicAdd(&lh[closest[row]], 1u);
  __syncthreads();
  blockhist[blockIdx.x * K_EMB + t] = lh[t];
}

// prefix over blocks+bins; also computes new_cluster (absorbs old finalize1 cluster math)
__global__ void hist2_kernel(unsigned int* __restrict__ blockhist, const float* __restrict__ cs,
                             unsigned int* __restrict__ base, float* __restrict__ newc,
                             float* __restrict__ o_ncl, int nblocks) {
  __shared__ unsigned int sc[K_EMB];
  __shared__ float fr[K_EMB];
  const int bin = threadIdx.x;  // 1024
  unsigned int s = 0;
  for (int b = 0; b < nblocks; ++b) {
    const unsigned int v = blockhist[b * K_EMB + bin];
    blockhist[b * K_EMB + bin] = s;
    s += v;
  }
  sc[bin] = s;
  __syncthreads();
  for (int off = 1; off < K_EMB; off <<= 1) {
    const unsigned int t = (bin >= off) ? sc[bin - off] : 0u;
    __syncthreads();
    sc[bin] += t;
    __syncthreads();
  }
  base[bin] = sc[bin] - s;  // exclusive prefix
  const float pre = cs[bin] * 0.99f + (float)s * (float)(1.0 - 0.99);
  fr[bin] = pre;
  __syncthreads();
  for (int st = 512; st > 0; st >>= 1) {
    if (bin < st) fr[bin] += fr[bin + st];
    __syncthreads();
  }
  const float n = fr[0];
  const float ncl = (pre + 1e-5f) / (n + (float)(K_EMB * 1e-5)) * n;
  newc[bin] = ncl;
  o_ncl[bin] = ncl;
}

__global__ void hist3_kernel(const int* __restrict__ closest, const unsigned int* __restrict__ rank,
                             const unsigned int* __restrict__ blockhist,
                             const unsigned int* __restrict__ base,
                             unsigned int* __restrict__ sorted) {
  const int t = threadIdx.x;
  const int row = blockIdx.x * 1024 + t;
  const int k = closest[row];
  sorted[base[k] + blockhist[blockIdx.x * K_EMB + k] + rank[row]] = (unsigned int)row;
}

// ============================ st_quantized + loss (pure stream, no atomics) ============================

__global__ void st_loss_kernel(const float* __restrict__ z, const float* __restrict__ emb,
                               const int* __restrict__ closest, float* __restrict__ st_out,
                               float* __restrict__ loss_part) {
  const int row = blockIdx.x * 4 + (threadIdx.x >> 6);
  const int lane = threadIdx.x & 63;
  const int k = closest[row];
  const float4 zv = ((const float4*)(z + (size_t)row * D_EMB))[lane];
  const float4 ev = ((const float4*)(emb + (size_t)k * D_EMB))[lane];
  const float dx = ev.x - zv.x, dy = ev.y - zv.y, dz = ev.z - zv.z, dww = ev.w - zv.w;
  float* sp = st_out + (size_t)row * D_EMB + lane * 4;  // st region is 4B-offset: scalar stores
  sp[0] = zv.x + dx; sp[1] = zv.y + dy; sp[2] = zv.z + dz; sp[3] = zv.w + dww;
  float ls = dx * dx + dy * dy + dz * dz + dww * dww;
#pragma unroll
  for (int off = 32; off > 0; off >>= 1) ls += __shfl_down(ls, off, 64);
  __shared__ float lsum[4];
  if (lane == 0) lsum[threadIdx.x >> 6] = ls;
  __syncthreads();
  if (threadIdx.x == 0) loss_part[blockIdx.x] = (lsum[0] + lsum[1]) + (lsum[2] + lsum[3]);
}

__global__ void loss_final_kernel(const float* __restrict__ loss_part, int nlp,
                                  float* __restrict__ o_loss, int nrows) {
  const int i = threadIdx.x;  // 1024
  double lp = 0.0;
  for (int t = i; t < nlp; t += 1024) lp += (double)loss_part[t];
  __shared__ double dred[1024];
  dred[i] = lp;
  __syncthreads();
  for (int s = 512; s > 0; s >>= 1) {
    if (i < s) dred[i] += dred[i + s];
    __syncthreads();
  }
  if (i == 0) o_loss[0] = (float)(0.25 * (dred[0] / ((double)nrows * (double)D_EMB)));
}

// ============================ segmented dw sum + EMA finalize (no atomics) ============================

__global__ void dwsum_kernel(const float* __restrict__ z, const unsigned int* __restrict__ sorted,
                             const unsigned int* __restrict__ base, const float* __restrict__ ema,
                             const float* __restrict__ newc, float* __restrict__ o_nema,
                             float* __restrict__ o_nemb, int N) {
  const int k = blockIdx.x;
  const int lane = threadIdx.x & 63, wv = threadIdx.x >> 6;
  const unsigned int b0 = base[k];
  const unsigned int b1 = (k == K_EMB - 1) ? (unsigned int)N : base[k + 1];
  float4 acc = {0.f, 0.f, 0.f, 0.f};
  for (unsigned int j = b0 + wv; j < b1; j += 4) {
    const unsigned int row = sorted[j];
    const float4 v = ((const float4*)(z + (size_t)row * D_EMB))[lane];
    acc.x += v.x; acc.y += v.y; acc.z += v.z; acc.w += v.w;
  }
  __shared__ float4 red[256];
  red[threadIdx.x] = acc;
  __syncthreads();
  if (wv == 0) {
    const float4 a1 = red[64 + lane], a2 = red[128 + lane], a3 = red[192 + lane];
    acc = red[lane];
    acc.x += a1.x + a2.x + a3.x;
    acc.y += a1.y + a2.y + a3.y;
    acc.z += a1.z + a2.z + a3.z;
    acc.w += a1.w + a2.w + a3.w;
    const float4 ev = ((const float4*)ema)[k * 64 + lane];
    const float nc = newc[k];
    const int off = k * D_EMB + lane * 4;  // outputs are 4B-offset: scalar stores
    float ne;
    ne = ev.x * 0.99f + acc.x * (float)(1.0 - 0.99); o_nema[off + 0] = ne; o_nemb[off + 0] = ne / nc;
    ne = ev.y * 0.99f + acc.y * (float)(1.0 - 0.99); o_nema[off + 1] = ne; o_nemb[off + 1] = ne / nc;
    ne = ev.z * 0.99f + acc.z * (float)(1.0 - 0.99); o_nema[off + 2] = ne; o_nemb[off + 2] = ne / nc;
    ne = ev.w * 0.99f + acc.w * (float)(1.0 - 0.99); o_nema[off + 3] = ne; o_nemb[off + 3] = ne / nc;
  }
}

// ============================ launcher ============================

extern "C" void kernel_launch(void* const* d_in, const int* in_sizes, int n_in,
                              void* d_out, int out_size, void* d_ws, size_t ws_size,
                              hipStream_t stream) {
  const float* z = (const float*)d_in[0];
  const float* emb = (const float*)d_in[1];
  const float* ema = (const float*)d_in[2];
  const float* cs = (const float*)d_in[3];
  const int N = in_sizes[0] / D_EMB;  // 65536
  const int NB = N / 1024;            // 64

  float* out = (float*)d_out;
  float* o_loss = out;
  float* o_st = out + 1;
  float* o_idx = o_st + (size_t)N * D_EMB;
  float* o_nemb = o_idx + N;
  float* o_ncl = o_nemb + (size_t)K_EMB * D_EMB;
  float* o_nema = o_ncl + K_EMB;

  float* ws = (float*)d_ws;
  float* t1 = ws;                                              // N
  float* t2 = t1 + N;                                          // K
  int* closest = (int*)(t2 + K_EMB);                           // N
  float* newc = (float*)(closest + N);                         // K
  _Float16* ehp = (_Float16*)(newc + K_EMB);                   // K*D f16
  unsigned int* flaglist = (unsigned int*)(ehp + (size_t)K_EMB * D_EMB);  // N (alias: rank)
  unsigned int* blockhist = flaglist + N;                      // NB*K (alias: loss_part)
  unsigned int* basep = blockhist + (size_t)NB * K_EMB;        // K
  unsigned int* sorted = basep + K_EMB;                        // N
  unsigned int* flag_cnt = sorted + N;                         // 1 (zeroed each call)

  unsigned int* rank = flaglist;          // safe: flaglist consumed by fixup before hist1
  float* loss_part = (float*)blockhist;   // safe: blockhist consumed by hist3 before st_loss

  // zh (N*D f16 = 32 MB) lives in the o_st output region (overwritten by st_loss later)
  uintptr_t zp_ = ((uintptr_t)o_st + 15) & ~(uintptr_t)15;
  _Float16* zh = (_Float16*)zp_;

  hipMemsetAsync(flag_cnt, 0, 4, stream);
  convert_z_kernel<<<N / 4, 256, 0, stream>>>(z, zh, t1);
  convert_e_kernel<<<K_EMB / 4, 256, 0, stream>>>(emb, ehp, t2);
  argmin_mfma_kernel<<<N / BM, 512, 0, stream>>>(zh, ehp, t2, closest, o_idx, flag_cnt, flaglist);
  fixup_kernel<<<256, 256, 0, stream>>>(z, emb, t1, t2, flag_cnt, flaglist, closest, o_idx);
  hist1_kernel<<<NB, 1024, 0, stream>>>(closest, rank, blockhist);
  hist2_kernel<<<1, 1024, 0, stream>>>(blockhist, cs, basep, newc, o_ncl, NB);
  hist3_kernel<<<NB, 1024, 0, stream>>>(closest, rank, blockhist, basep, sorted);
  st_loss_kernel<<<N / 4, 256, 0, stream>>>(z, emb, closest, o_st, loss_part);
  loss_final_kernel<<<1, 1024, 0, stream>>>(loss_part, N / 4, o_loss, N);
  dwsum_kernel<<<K_EMB, 256, 0, stream>>>(z, sorted, basep, ema, newc, o_nema, o_nemb, N);
}